// Round 14
// baseline (165.502 us; speedup 1.0000x reference)
//
#include <hip/hip_runtime.h>
#include <hip/hip_fp16.h>

#define IMG_H 1024
#define IMG_W 1024
#define NIMG  16
#define RAD   5
#define KW    11
#define TX    64              // tile width (cols)
#define STRIP 128             // tile height (rows per block)
#define ASTEP 16              // h-blur rows per A phase
#define BSTEP 32              // output rows per B phase
#define HBROWS (STRIP + 2*RAD)   // 138 h-blurred rows per strip
#define RING  48              // LDS ring rows
#define PADW  68              // halfs per ring row (136 B)
#define NPIX  (NIMG * IMG_H * IMG_W)

// Gaussian(sigma=1.5, 11 taps), normalized fp32 — matches reference window.
__device__ __forceinline__ float gw(int k) {
    constexpr float G[KW] = {
        0.00102838f, 0.00759876f, 0.03600077f, 0.10936070f, 0.21300554f,
        0.26601173f,
        0.21300554f, 0.10936070f, 0.03600077f, 0.00759876f, 0.00102838f};
    return G[k];
}

__device__ __forceinline__ unsigned h2u(__half2 v) {
    union { __half2 h; unsigned u; } c; c.h = v; return c.u;
}
__device__ __forceinline__ __half2 u2h(unsigned v) {
    union { unsigned u; __half2 h; } c; c.u = v; return c.h;
}
// halfs (w[idx], w[idx+1]) from packed word array; odd idx = v_alignbit.
// idx is compile-time under full unroll (rule #20 safe).
__device__ __forceinline__ __half2 hsel(const unsigned* hw, int idx) {
    unsigned r;
    if (idx & 1) r = (hw[idx >> 1] >> 16) | (hw[(idx >> 1) + 1] << 16);
    else         r = hw[idx >> 1];
    return u2h(r);
}

// Raw pixel window for one Phase-A unit: named members (no arrays passed by
// pointer — R8-R12's "spill" was SROA failure on array-pointer lambdas).
struct Raw {
    float4 x0, x1, x2, x3, x4;
    float4 y0, y1, y2, y3, y4;
};

// T14 loads-early schedule: loadRaw(a) issues 10 global float4 (~40 VGPR,
// no LDS deps) BEFORE phaseB(s); blurStore consumes after the barrier.
// Needs >64 VGPR -> launch_bounds(256,4); LDS 32.6 KB; ~4 blocks/CU.
__global__ __launch_bounds__(256, 4) void ssim_strip_kernel(
        const float* __restrict__ img1, const float* __restrict__ img2,
        float* __restrict__ partial, int atomic_mode) {
    __shared__ __align__(16) __half hb[5][RING][PADW];
    __shared__ float wsum[4];

    const int t = threadIdx.x;
    const int tile_x = blockIdx.x * TX;
    const int tile_y = blockIdx.y * STRIP;
    const size_t img_off = (size_t)blockIdx.z * (IMG_H * IMG_W);
    const float* p1 = img1 + img_off;
    const float* p2 = img2 + img_off;

    const bool x_ok = (tile_x >= 8) && (tile_x + 72 <= IMG_W);

    // guarded float4 pair load (border path only)
    auto ldpair = [&](const float* r1, const float* r2, int gc, bool rowok,
                      float4& xa, float4& ya) {
        xa = make_float4(0.f, 0.f, 0.f, 0.f);
        ya = make_float4(0.f, 0.f, 0.f, 0.f);
        if (rowok) {
            if (gc >= 0 && gc <= IMG_W - 4) {
                xa = *reinterpret_cast<const float4*>(r1 + gc);
                ya = *reinterpret_cast<const float4*>(r2 + gc);
            } else if (gc > -4 && gc < IMG_W) {
                float* ex = &xa.x;
                float* ey = &ya.x;
#pragma unroll
                for (int j = 0; j < 4; ++j) {
                    int g = gc + j;
                    if ((unsigned)g < (unsigned)IMG_W) {
                        ex[j] = r1[g];
                        ey[j] = r2[g];
                    }
                }
            }
        }
    };

    // Issue the 10 global loads for A-step a. No LDS interaction.
    auto loadRaw = [&](int a) -> Raw {
        Raw rw;
        const int tr = t >> 4;
        const int g4 = t & 15;
        const int h = ASTEP * a + tr;
        const int gr = tile_y + h - RAD;
        const int gc0 = tile_x + g4 * 4 - 8;
        const bool row_ok = (tile_y + ASTEP * a - RAD >= 0) &&
                            (tile_y + ASTEP * a + ASTEP - 1 - RAD < IMG_H);
        if (h < HBROWS && x_ok && row_ok) {
            const float* b1 = p1 + (size_t)gr * IMG_W + gc0;
            const float* b2 = p2 + (size_t)gr * IMG_W + gc0;
            rw.x0 = *reinterpret_cast<const float4*>(b1);
            rw.x1 = *reinterpret_cast<const float4*>(b1 + 4);
            rw.x2 = *reinterpret_cast<const float4*>(b1 + 8);
            rw.x3 = *reinterpret_cast<const float4*>(b1 + 12);
            rw.x4 = *reinterpret_cast<const float4*>(b1 + 16);
            rw.y0 = *reinterpret_cast<const float4*>(b2);
            rw.y1 = *reinterpret_cast<const float4*>(b2 + 4);
            rw.y2 = *reinterpret_cast<const float4*>(b2 + 8);
            rw.y3 = *reinterpret_cast<const float4*>(b2 + 12);
            rw.y4 = *reinterpret_cast<const float4*>(b2 + 16);
        } else {
            const bool rowok = (h < HBROWS) && ((unsigned)gr < (unsigned)IMG_H);
            const float* r1 = p1 + (size_t)gr * IMG_W;
            const float* r2 = p2 + (size_t)gr * IMG_W;
            ldpair(r1, r2, gc0,      rowok, rw.x0, rw.y0);
            ldpair(r1, r2, gc0 + 4,  rowok, rw.x1, rw.y1);
            ldpair(r1, r2, gc0 + 8,  rowok, rw.x2, rw.y2);
            ldpair(r1, r2, gc0 + 12, rowok, rw.x3, rw.y3);
            ldpair(r1, r2, gc0 + 16, rowok, rw.x4, rw.y4);
        }
        return rw;
    };

    // cvt + packed-fp16 h-blur + ring store for A-step a.
    auto blurStore = [&](const Raw& rw, int a) {
        const int tr = t >> 4;
        const int g4 = t & 15;
        const int h = ASTEP * a + tr;
        if (h >= HBROWS) return;
        int rr = h;
        if (rr >= 96) rr -= 96;
        else if (rr >= RING) rr -= RING;
        unsigned hwx[10], hwy[10];
        hwx[0] = h2u(__floats2half2_rn(rw.x0.x, rw.x0.y));
        hwx[1] = h2u(__floats2half2_rn(rw.x0.z, rw.x0.w));
        hwx[2] = h2u(__floats2half2_rn(rw.x1.x, rw.x1.y));
        hwx[3] = h2u(__floats2half2_rn(rw.x1.z, rw.x1.w));
        hwx[4] = h2u(__floats2half2_rn(rw.x2.x, rw.x2.y));
        hwx[5] = h2u(__floats2half2_rn(rw.x2.z, rw.x2.w));
        hwx[6] = h2u(__floats2half2_rn(rw.x3.x, rw.x3.y));
        hwx[7] = h2u(__floats2half2_rn(rw.x3.z, rw.x3.w));
        hwx[8] = h2u(__floats2half2_rn(rw.x4.x, rw.x4.y));
        hwx[9] = h2u(__floats2half2_rn(rw.x4.z, rw.x4.w));
        hwy[0] = h2u(__floats2half2_rn(rw.y0.x, rw.y0.y));
        hwy[1] = h2u(__floats2half2_rn(rw.y0.z, rw.y0.w));
        hwy[2] = h2u(__floats2half2_rn(rw.y1.x, rw.y1.y));
        hwy[3] = h2u(__floats2half2_rn(rw.y1.z, rw.y1.w));
        hwy[4] = h2u(__floats2half2_rn(rw.y2.x, rw.y2.y));
        hwy[5] = h2u(__floats2half2_rn(rw.y2.z, rw.y2.w));
        hwy[6] = h2u(__floats2half2_rn(rw.y3.x, rw.y3.y));
        hwy[7] = h2u(__floats2half2_rn(rw.y3.z, rw.y3.w));
        hwy[8] = h2u(__floats2half2_rn(rw.y4.x, rw.y4.y));
        hwy[9] = h2u(__floats2half2_rn(rw.y4.z, rw.y4.w));

        __half2 A0[2], A1[2], A2[2], A3[2], A4[2];
#pragma unroll
        for (int p = 0; p < 2; ++p)
            A0[p] = A1[p] = A2[p] = A3[p] = A4[p] = u2h(0u);
#pragma unroll
        for (int k = 0; k < KW; ++k) {
            const __half2 g2 = __float2half2_rn(gw(k));
#pragma unroll
            for (int p = 0; p < 2; ++p) {
                const int idx = 2 * p + 3 + k;
                const __half2 X = hsel(hwx, idx);
                const __half2 Y = hsel(hwy, idx);
                A0[p] = __hfma2(g2, X, A0[p]);
                A1[p] = __hfma2(g2, Y, A1[p]);
                const __half2 gx = __hmul2(g2, X);
                const __half2 gy = __hmul2(g2, Y);
                A2[p] = __hfma2(gx, X, A2[p]);
                A3[p] = __hfma2(gy, Y, A3[p]);
                A4[p] = __hfma2(gx, Y, A4[p]);
            }
        }
        *reinterpret_cast<uint2*>(&hb[0][rr][g4 * 4]) = make_uint2(h2u(A0[0]), h2u(A0[1]));
        *reinterpret_cast<uint2*>(&hb[1][rr][g4 * 4]) = make_uint2(h2u(A1[0]), h2u(A1[1]));
        *reinterpret_cast<uint2*>(&hb[2][rr][g4 * 4]) = make_uint2(h2u(A2[0]), h2u(A2[1]));
        *reinterpret_cast<uint2*>(&hb[3][rr][g4 * 4]) = make_uint2(h2u(A3[0]), h2u(A3[1]));
        *reinterpret_cast<uint2*>(&hb[4][rr][g4 * 4]) = make_uint2(h2u(A4[0]), h2u(A4[1]));
    };

    float lsum = 0.f;

    // Phase B step s: v-blur + SSIM for output rows 32s..32s+31.
    auto phaseB = [&](int s) {
        __half2 gh2[KW];
#pragma unroll
        for (int k = 0; k < KW; ++k) gh2[k] = __float2half2_rn(gw(k));

        const int rbase = (BSTEP * s) % RING;   // 0,32,16,0
        const int slot = t & 15;
        const int r2 = (t >> 4) * 2;
        __half2 acc[5][2][2];
#pragma unroll
        for (int q = 0; q < 5; ++q)
#pragma unroll
            for (int rl = 0; rl < 2; ++rl)
#pragma unroll
                for (int cp = 0; cp < 2; ++cp)
                    acc[q][rl][cp] = u2h(0u);

#pragma unroll
        for (int q = 0; q < 5; ++q) {
#pragma unroll
            for (int k = 0; k < KW + 1; ++k) {
                int r = rbase + r2 + k;
                if (r >= RING) r -= RING;
                const uint2 rv =
                    *reinterpret_cast<const uint2*>(&hb[q][r][slot * 4]);
                __half2 h0 = u2h(rv.x);
                __half2 h1 = u2h(rv.y);
                if (k < KW) {
                    acc[q][0][0] = __hfma2(gh2[k], h0, acc[q][0][0]);
                    acc[q][0][1] = __hfma2(gh2[k], h1, acc[q][0][1]);
                }
                if (k > 0) {
                    acc[q][1][0] = __hfma2(gh2[k - 1], h0, acc[q][1][0]);
                    acc[q][1][1] = __hfma2(gh2[k - 1], h1, acc[q][1][1]);
                }
            }
        }

        const float C1 = 0.0001f;
        const float C2 = 0.0009f;
#pragma unroll
        for (int rl = 0; rl < 2; ++rl) {
#pragma unroll
            for (int cp = 0; cp < 2; ++cp) {
                float2 m1p  = __half22float2(acc[0][rl][cp]);
                float2 m2p  = __half22float2(acc[1][rl][cp]);
                float2 b11p = __half22float2(acc[2][rl][cp]);
                float2 b22p = __half22float2(acc[3][rl][cp]);
                float2 b12p = __half22float2(acc[4][rl][cp]);
#pragma unroll
                for (int e = 0; e < 2; ++e) {
                    float m1 = e ? m1p.y : m1p.x;
                    float m2 = e ? m2p.y : m2p.x;
                    float b11 = e ? b11p.y : b11p.x;
                    float b22 = e ? b22p.y : b22p.x;
                    float b12 = e ? b12p.y : b12p.x;
                    float m1s = m1 * m1;
                    float m2s = m2 * m2;
                    float m12 = m1 * m2;
                    float num = (2.f * m12 + C1) * (2.f * (b12 - m12) + C2);
                    float den = (m1s + m2s + C1) *
                                ((b11 - m1s) + (b22 - m2s) + C2);
                    lsum = fmaf(num, __builtin_amdgcn_rcpf(den), lsum);
                }
            }
        }
    };

    // ---- fill: A0,A1,A2 (stagger loads for MLP) ----
    {
        Raw ra = loadRaw(0);
        Raw rb = loadRaw(1);
        blurStore(ra, 0);
        ra = loadRaw(2);
        blurStore(rb, 1);
        blurStore(ra, 2);
    }
    __syncthreads();

    // ---- steady state, 7-barrier T14 schedule ----
    // Ring safety (verified): BS(3+2s)/BS(4+2s) only overwrite rows whose
    // last reader (B(s)) ran before the intervening barrier.
#pragma unroll 1
    for (int s = 0; s < 3; ++s) {
        Raw ra = loadRaw(3 + 2 * s);   // loads fly under phaseB
        phaseB(s);
        __syncthreads();
        blurStore(ra, 3 + 2 * s);
        Raw rb = loadRaw(4 + 2 * s);   // hoists above blurStore's VALU
        blurStore(rb, 4 + 2 * s);
        __syncthreads();
    }
    phaseB(3);

    // ---- block reduction ----
#pragma unroll
    for (int off = 32; off > 0; off >>= 1)
        lsum += __shfl_down(lsum, off, 64);
    if ((t & 63) == 0) wsum[t >> 6] = lsum;
    __syncthreads();
    if (t == 0) {
        float s = wsum[0] + wsum[1] + wsum[2] + wsum[3];
        if (atomic_mode) {
            atomicAdd(partial, s);
        } else {
            int bid = (blockIdx.z * gridDim.y + blockIdx.y) * gridDim.x + blockIdx.x;
            partial[bid] = s;
        }
    }
}

__global__ __launch_bounds__(256) void ssim_reduce_kernel(
        const float* __restrict__ partial, int n, float* __restrict__ out) {
    float s = 0.f;
    for (int i = threadIdx.x; i < n; i += 256) s += partial[i];
#pragma unroll
    for (int off = 32; off > 0; off >>= 1)
        s += __shfl_down(s, off, 64);
    __shared__ float ws[4];
    if ((threadIdx.x & 63) == 0) ws[threadIdx.x >> 6] = s;
    __syncthreads();
    if (threadIdx.x == 0) {
        float tot = ws[0] + ws[1] + ws[2] + ws[3];
        out[0] = 1.f - tot / (float)NPIX;
    }
}

extern "C" void kernel_launch(void* const* d_in, const int* in_sizes, int n_in,
                              void* d_out, int out_size, void* d_ws, size_t ws_size,
                              hipStream_t stream) {
    const float* img1 = (const float*)d_in[0];
    const float* img2 = (const float*)d_in[1];
    float* out = (float*)d_out;
    float* partial = (float*)d_ws;

    dim3 grid(IMG_W / TX, IMG_H / STRIP, NIMG);   // 16 x 8 x 16 = 2048 blocks
    const int nblocks = (IMG_W / TX) * (IMG_H / STRIP) * NIMG;
    const size_t needed = (size_t)nblocks * sizeof(float);

    if (ws_size >= needed) {
        ssim_strip_kernel<<<grid, 256, 0, stream>>>(img1, img2, partial, 0);
        ssim_reduce_kernel<<<1, 256, 0, stream>>>(partial, nblocks, out);
    } else {
        hipMemsetAsync(d_ws, 0, sizeof(float), stream);
        ssim_strip_kernel<<<grid, 256, 0, stream>>>(img1, img2, partial, 1);
        ssim_reduce_kernel<<<1, 256, 0, stream>>>(partial, 1, out);
    }
}

// Round 15
// 76.638 us; speedup vs baseline: 2.1595x; 2.1595x over previous
//
#include <hip/hip_runtime.h>
#include <hip/hip_fp16.h>

#define IMG_H 1024
#define IMG_W 1024
#define NIMG  16
#define RAD   5
#define KW    11
#define TX    64              // tile width (cols)
#define STRIP 128             // tile height (rows per block)
#define ASTEP 16              // h-blur rows per A phase
#define BSTEP 32              // output rows per B phase
#define HBROWS (STRIP + 2*RAD)   // 138 h-blurred rows per strip
#define RING  48              // LDS ring rows
#define PADW  68              // halfs per ring row (136 B)
#define NQ    4               // ring quantities: x, y, xx+yy, xy
#define NPIX  (NIMG * IMG_H * IMG_W)

// Gaussian(sigma=1.5, 11 taps), normalized fp32 — matches reference window.
__device__ __forceinline__ float gw(int k) {
    constexpr float G[KW] = {
        0.00102838f, 0.00759876f, 0.03600077f, 0.10936070f, 0.21300554f,
        0.26601173f,
        0.21300554f, 0.10936070f, 0.03600077f, 0.00759876f, 0.00102838f};
    return G[k];
}

__device__ __forceinline__ unsigned h2u(__half2 v) {
    union { __half2 h; unsigned u; } c; c.h = v; return c.u;
}
__device__ __forceinline__ __half2 u2h(unsigned v) {
    union { unsigned u; __half2 h; } c; c.u = v; return c.h;
}
// halfs (w[idx], w[idx+1]) from packed word array; odd idx = v_alignbit.
// idx is compile-time under full unroll (rule #20 safe).
__device__ __forceinline__ __half2 hsel(const unsigned* hw, int idx) {
    unsigned r;
    if (idx & 1) r = (hw[idx >> 1] >> 16) | (hw[(idx >> 1) + 1] << 16);
    else         r = hw[idx >> 1];
    return u2h(r);
}

// R13 body (proven: 79.6 us, VGPR 60, no spill) + 4-quantity algebra:
// SSIM needs only blur(x), blur(y), blur(xx+yy), blur(xy) —
// sigma1_sq+sigma2_sq = blur(xx+yy) - mu1^2 - mu2^2. 20% less LDS
// capacity/traffic/fma; ring 26,112 B -> 6 blocks/CU.
__global__ __launch_bounds__(256, 8) void ssim_strip_kernel(
        const float* __restrict__ img1, const float* __restrict__ img2,
        float* __restrict__ partial, int atomic_mode) {
    __shared__ __align__(16) __half hb[NQ][RING][PADW];
    __shared__ float wsum[4];

    const int t = threadIdx.x;
    const int tile_x = blockIdx.x * TX;
    const int tile_y = blockIdx.y * STRIP;
    const size_t img_off = (size_t)blockIdx.z * (IMG_H * IMG_W);
    const float* p1 = img1 + img_off;
    const float* p2 = img2 + img_off;

    const bool x_ok = (tile_x >= 8) && (tile_x + 72 <= IMG_W);

    // Phase A step a: h-blur halo rows h = 16a+(t>>4) into ring slot h%48.
    // One 4-col unit per thread; window kept as packed fp16 words.
    auto phaseA = [&](int a) {
        const int tr = t >> 4;
        const int g4 = t & 15;
        const int h = ASTEP * a + tr;
        if (h >= HBROWS) return;
        int rr = h;
        if (rr >= 96) rr -= 96;
        else if (rr >= RING) rr -= RING;
        const int gr = tile_y + h - RAD;
        const int gc0 = tile_x + g4 * 4 - 8;
        const bool row_ok = (tile_y + ASTEP * a - RAD >= 0) &&
                            (tile_y + ASTEP * a + ASTEP - 1 - RAD < IMG_H);
        unsigned hwx[10], hwy[10];
        if (x_ok && row_ok) {
            const size_t base = (size_t)gr * IMG_W + gc0;
#pragma unroll
            for (int w = 0; w < 5; ++w) {
                const float4 xa = *reinterpret_cast<const float4*>(p1 + base + 4 * w);
                const float4 ya = *reinterpret_cast<const float4*>(p2 + base + 4 * w);
                hwx[2 * w]     = h2u(__floats2half2_rn(xa.x, xa.y));
                hwx[2 * w + 1] = h2u(__floats2half2_rn(xa.z, xa.w));
                hwy[2 * w]     = h2u(__floats2half2_rn(ya.x, ya.y));
                hwy[2 * w + 1] = h2u(__floats2half2_rn(ya.z, ya.w));
            }
        } else {
            const bool rowok = ((unsigned)gr < (unsigned)IMG_H);
            const float* row1 = p1 + (size_t)gr * IMG_W;
            const float* row2 = p2 + (size_t)gr * IMG_W;
#pragma unroll
            for (int w = 0; w < 5; ++w) {
                const int gc = gc0 + 4 * w;
                float4 xa = make_float4(0.f, 0.f, 0.f, 0.f);
                float4 ya = make_float4(0.f, 0.f, 0.f, 0.f);
                if (rowok) {
                    if (gc >= 0 && gc <= IMG_W - 4) {
                        xa = *reinterpret_cast<const float4*>(row1 + gc);
                        ya = *reinterpret_cast<const float4*>(row2 + gc);
                    } else if (gc > -4 && gc < IMG_W) {
                        float* ex = &xa.x;
                        float* ey = &ya.x;
#pragma unroll
                        for (int j = 0; j < 4; ++j) {
                            int g = gc + j;
                            if ((unsigned)g < (unsigned)IMG_W) {
                                ex[j] = row1[g];
                                ey[j] = row2[g];
                            }
                        }
                    }
                }
                hwx[2 * w]     = h2u(__floats2half2_rn(xa.x, xa.y));
                hwx[2 * w + 1] = h2u(__floats2half2_rn(xa.z, xa.w));
                hwy[2 * w]     = h2u(__floats2half2_rn(ya.x, ya.y));
                hwy[2 * w + 1] = h2u(__floats2half2_rn(ya.z, ya.w));
            }
        }
        // packed-fp16 h-blur: 4 cols = 2 half2 lanes per quantity.
        // A2 accumulates g*(xx+yy) directly (two fma, one accumulator).
        __half2 A0[2], A1[2], A2[2], A3[2];
#pragma unroll
        for (int p = 0; p < 2; ++p)
            A0[p] = A1[p] = A2[p] = A3[p] = u2h(0u);
#pragma unroll
        for (int k = 0; k < KW; ++k) {
            const __half2 g2 = __float2half2_rn(gw(k));
#pragma unroll
            for (int p = 0; p < 2; ++p) {
                const int idx = 2 * p + 3 + k;
                const __half2 X = hsel(hwx, idx);
                const __half2 Y = hsel(hwy, idx);
                A0[p] = __hfma2(g2, X, A0[p]);
                A1[p] = __hfma2(g2, Y, A1[p]);
                const __half2 gx = __hmul2(g2, X);
                const __half2 gy = __hmul2(g2, Y);
                A2[p] = __hfma2(gx, X, A2[p]);
                A2[p] = __hfma2(gy, Y, A2[p]);
                A3[p] = __hfma2(gx, Y, A3[p]);
            }
        }
        *reinterpret_cast<uint2*>(&hb[0][rr][g4 * 4]) = make_uint2(h2u(A0[0]), h2u(A0[1]));
        *reinterpret_cast<uint2*>(&hb[1][rr][g4 * 4]) = make_uint2(h2u(A1[0]), h2u(A1[1]));
        *reinterpret_cast<uint2*>(&hb[2][rr][g4 * 4]) = make_uint2(h2u(A2[0]), h2u(A2[1]));
        *reinterpret_cast<uint2*>(&hb[3][rr][g4 * 4]) = make_uint2(h2u(A3[0]), h2u(A3[1]));
    };

    float lsum = 0.f;

    // Phase B step s: v-blur + SSIM for output rows 32s..32s+31.
    // thread: 4 cols (slot = t&15) x 2 rows (r2 = (t>>4)*2).
    auto phaseB = [&](int s) {
        __half2 gh2[KW];
#pragma unroll
        for (int k = 0; k < KW; ++k) gh2[k] = __float2half2_rn(gw(k));

        const int rbase = (BSTEP * s) % RING;   // 0,32,16,0
        const int slot = t & 15;
        const int r2 = (t >> 4) * 2;
        __half2 acc[NQ][2][2];
#pragma unroll
        for (int q = 0; q < NQ; ++q)
#pragma unroll
            for (int rl = 0; rl < 2; ++rl)
#pragma unroll
                for (int cp = 0; cp < 2; ++cp)
                    acc[q][rl][cp] = u2h(0u);

#pragma unroll
        for (int q = 0; q < NQ; ++q) {
#pragma unroll
            for (int k = 0; k < KW + 1; ++k) {
                int r = rbase + r2 + k;     // <= 32+30+11 = 73
                if (r >= RING) r -= RING;
                const uint2 rv =
                    *reinterpret_cast<const uint2*>(&hb[q][r][slot * 4]);
                __half2 h0 = u2h(rv.x);
                __half2 h1 = u2h(rv.y);
                if (k < KW) {
                    acc[q][0][0] = __hfma2(gh2[k], h0, acc[q][0][0]);
                    acc[q][0][1] = __hfma2(gh2[k], h1, acc[q][0][1]);
                }
                if (k > 0) {
                    acc[q][1][0] = __hfma2(gh2[k - 1], h0, acc[q][1][0]);
                    acc[q][1][1] = __hfma2(gh2[k - 1], h1, acc[q][1][1]);
                }
            }
        }

        const float C1 = 0.0001f;
        const float C2 = 0.0009f;
#pragma unroll
        for (int rl = 0; rl < 2; ++rl) {
#pragma unroll
            for (int cp = 0; cp < 2; ++cp) {
                float2 m1p = __half22float2(acc[0][rl][cp]);
                float2 m2p = __half22float2(acc[1][rl][cp]);
                float2 Sp  = __half22float2(acc[2][rl][cp]);   // blur(xx+yy)
                float2 Pp  = __half22float2(acc[3][rl][cp]);   // blur(xy)
#pragma unroll
                for (int e = 0; e < 2; ++e) {
                    float m1 = e ? m1p.y : m1p.x;
                    float m2 = e ? m2p.y : m2p.x;
                    float S  = e ? Sp.y  : Sp.x;
                    float P  = e ? Pp.y  : Pp.x;
                    float m1s = m1 * m1;
                    float m2s = m2 * m2;
                    float m12 = m1 * m2;
                    float sigsum = S - m1s - m2s;
                    float sig12  = P - m12;
                    float num = (2.f * m12 + C1) * (2.f * sig12 + C2);
                    float den = (m1s + m2s + C1) * (sigsum + C2);
                    lsum = fmaf(num, __builtin_amdgcn_rcpf(den), lsum);
                }
            }
        }
    };

    // R13's compact rolled schedule (best measured). Ring safety as
    // verified in R9/R11 (unchanged: same RING/ASTEP/BSTEP).
#pragma unroll 1
    for (int a = 0; a < 9; ++a) {
        phaseA(a);
        __syncthreads();
        if (a >= 2 && ((a & 1) == 0)) {
            phaseB((a - 2) >> 1);
            __syncthreads();
        }
    }

    // ---- block reduction ----
#pragma unroll
    for (int off = 32; off > 0; off >>= 1)
        lsum += __shfl_down(lsum, off, 64);
    if ((t & 63) == 0) wsum[t >> 6] = lsum;
    __syncthreads();
    if (t == 0) {
        float s = wsum[0] + wsum[1] + wsum[2] + wsum[3];
        if (atomic_mode) {
            atomicAdd(partial, s);
        } else {
            int bid = (blockIdx.z * gridDim.y + blockIdx.y) * gridDim.x + blockIdx.x;
            partial[bid] = s;
        }
    }
}

__global__ __launch_bounds__(256) void ssim_reduce_kernel(
        const float* __restrict__ partial, int n, float* __restrict__ out) {
    float s = 0.f;
    for (int i = threadIdx.x; i < n; i += 256) s += partial[i];
#pragma unroll
    for (int off = 32; off > 0; off >>= 1)
        s += __shfl_down(s, off, 64);
    __shared__ float ws[4];
    if ((threadIdx.x & 63) == 0) ws[threadIdx.x >> 6] = s;
    __syncthreads();
    if (threadIdx.x == 0) {
        float tot = ws[0] + ws[1] + ws[2] + ws[3];
        out[0] = 1.f - tot / (float)NPIX;
    }
}

extern "C" void kernel_launch(void* const* d_in, const int* in_sizes, int n_in,
                              void* d_out, int out_size, void* d_ws, size_t ws_size,
                              hipStream_t stream) {
    const float* img1 = (const float*)d_in[0];
    const float* img2 = (const float*)d_in[1];
    float* out = (float*)d_out;
    float* partial = (float*)d_ws;

    dim3 grid(IMG_W / TX, IMG_H / STRIP, NIMG);   // 16 x 8 x 16 = 2048 blocks
    const int nblocks = (IMG_W / TX) * (IMG_H / STRIP) * NIMG;
    const size_t needed = (size_t)nblocks * sizeof(float);

    if (ws_size >= needed) {
        ssim_strip_kernel<<<grid, 256, 0, stream>>>(img1, img2, partial, 0);
        ssim_reduce_kernel<<<1, 256, 0, stream>>>(partial, nblocks, out);
    } else {
        hipMemsetAsync(d_ws, 0, sizeof(float), stream);
        ssim_strip_kernel<<<grid, 256, 0, stream>>>(img1, img2, partial, 1);
        ssim_reduce_kernel<<<1, 256, 0, stream>>>(partial, 1, out);
    }
}